// Round 6
// baseline (194.169 us; speedup 1.0000x reference)
//
#include <hip/hip_runtime.h>
#include <hip/hip_cooperative_groups.h>
#include <cstdint>
#include <cstddef>

namespace cg = cooperative_groups;

typedef __bf16 bf16x8 __attribute__((ext_vector_type(8)));
typedef float  f32x4  __attribute__((ext_vector_type(4)));

#define N_ROWS 8192
#define KDIM   256
#define TEMP_INV 2.0f
#define LOG2E  1.4426950408889634f
#define EXPC   (TEMP_INV * LOG2E)

__device__ __forceinline__ ushort f2bf(float x) {
    uint32_t u = __float_as_uint(x);
    u += 0x7fffu + ((u >> 16) & 1u);
    return (ushort)(u >> 16);
}

// ---------------- 4-wave 128-tile GEMM core (validated rounds 3-4) ----------
__device__ __forceinline__ void stage_tiles(const ushort* __restrict__ xn,
        int rowBase, int colBase, int kb, ushort* As, ushort* Bs, int wave, int lane)
{
    #pragma unroll
    for (int it = 0; it < 4; ++it) {
        int ci = it * 256 + wave * 64 + lane;
        int row = ci >> 3;
        int c = (ci & 7) ^ (row & 7);                  // T2 pre-swizzled source
        const ushort* gA = xn + (size_t)(rowBase + row) * KDIM + kb + c * 8;
        const ushort* gB = xn + (size_t)(colBase + row) * KDIM + kb + c * 8;
        ushort* lA = As + (size_t)(it * 256 + wave * 64) * 8;
        ushort* lB = Bs + (size_t)(it * 256 + wave * 64) * 8;
        __builtin_amdgcn_global_load_lds((const __attribute__((address_space(1))) void*)gA,
                                         (__attribute__((address_space(3))) void*)lA, 16, 0, 0);
        __builtin_amdgcn_global_load_lds((const __attribute__((address_space(1))) void*)gB,
                                         (__attribute__((address_space(3))) void*)lB, 16, 0, 0);
    }
}

__device__ __forceinline__ void read_frags(const ushort* As, const ushort* Bs,
        bf16x8 (&a)[2][4], bf16x8 (&b)[2][4], int wave, int lane)
{
    const int wr = wave >> 1, wc = wave & 1;
    const int lrow = lane & 15, kgrp = lane >> 4;
    #pragma unroll
    for (int kk = 0; kk < 2; ++kk) {
        const int c = kk * 4 + kgrp;
        #pragma unroll
        for (int mi = 0; mi < 4; ++mi) {
            const int row = wr*64 + mi*16 + lrow;
            a[kk][mi] = *reinterpret_cast<const bf16x8*>(As + (size_t)row * 64 + ((c ^ (row & 7)) * 8));
        }
        #pragma unroll
        for (int ni = 0; ni < 4; ++ni) {
            const int row = wc*64 + ni*16 + lrow;
            b[kk][ni] = *reinterpret_cast<const bf16x8*>(Bs + (size_t)row * 64 + ((c ^ (row & 7)) * 8));
        }
    }
}

__device__ __forceinline__ void mfma_frags(bf16x8 (&a)[2][4], bf16x8 (&b)[2][4],
                                           f32x4 (&acc)[4][4])
{
    #pragma unroll
    for (int kk = 0; kk < 2; ++kk)
        #pragma unroll
        for (int mi = 0; mi < 4; ++mi)
            #pragma unroll
            for (int ni = 0; ni < 4; ++ni)
                acc[mi][ni] = __builtin_amdgcn_mfma_f32_16x16x32_bf16(a[kk][mi], b[kk][ni], acc[mi][ni], 0, 0, 0);
}

#define PIPE_READS_RELEASE(Ac, Bc)                                   \
    bf16x8 a[2][4], b[2][4];                                         \
    read_frags(Ac, Bc, a, b, wave, lane);                            \
    __builtin_amdgcn_sched_barrier(0);                               \
    asm volatile("s_waitcnt lgkmcnt(0)" ::: "memory");               \
    __builtin_amdgcn_sched_barrier(0);                               \
    __builtin_amdgcn_s_barrier();                                    \
    __builtin_amdgcn_sched_barrier(0);

#define PIPE_MFMA()                                                  \
    __builtin_amdgcn_s_setprio(1);                                   \
    mfma_frags(a, b, acc);                                           \
    __builtin_amdgcn_s_setprio(0);

#define PIPE_TAIL(N)                                                 \
    __builtin_amdgcn_sched_barrier(0);                               \
    asm volatile("s_waitcnt vmcnt(" #N ")" ::: "memory");            \
    __builtin_amdgcn_s_barrier();                                    \
    __builtin_amdgcn_sched_barrier(0);

__device__ __forceinline__ void kloop_pipe(const ushort* __restrict__ xn,
        int rowBase, int colBase, f32x4 (&acc)[4][4],
        ushort* As0, ushort* Bs0, ushort* As1, ushort* Bs1, int wave, int lane)
{
    stage_tiles(xn, rowBase, colBase, 0,  As0, Bs0, wave, lane);
    stage_tiles(xn, rowBase, colBase, 64, As1, Bs1, wave, lane);
    asm volatile("s_waitcnt vmcnt(8)" ::: "memory");
    __builtin_amdgcn_s_barrier();
    __builtin_amdgcn_sched_barrier(0);
    {
        PIPE_READS_RELEASE(As0, Bs0)
        stage_tiles(xn, rowBase, colBase, 128, As0, Bs0, wave, lane);
        PIPE_MFMA()
        PIPE_TAIL(8)
    }
    {
        PIPE_READS_RELEASE(As1, Bs1)
        stage_tiles(xn, rowBase, colBase, 192, As1, Bs1, wave, lane);
        PIPE_MFMA()
        PIPE_TAIL(8)
    }
    {
        PIPE_READS_RELEASE(As0, Bs0)
        PIPE_MFMA()
        PIPE_TAIL(0)
    }
    {
        PIPE_READS_RELEASE(As1, Bs1)
        PIPE_MFMA()
    }
}

// ---------------- single fused cooperative kernel ----------------
__global__ __launch_bounds__(256) void fused_all(const float* __restrict__ logits,
        const int* __restrict__ label, float* __restrict__ out,
        ushort* __restrict__ xn, float* __restrict__ pD,
        int* __restrict__ perm, int* __restrict__ labelPerm,
        int* __restrict__ classStartG, int* __restrict__ cumTilesG,
        float* __restrict__ partial, unsigned int* __restrict__ counter)
{
    cg::grid_group grid = cg::this_grid();

    __shared__ __align__(16) char pool[65536];
    __shared__ int   labLDS[256];
    __shared__ float redF[256];
    __shared__ float DarrL[128];
    __shared__ int   cstart[11];
    __shared__ int   ccount[10];
    __shared__ int   lastFlag;

    ushort* As0 = (ushort*)(pool);
    ushort* Bs0 = (ushort*)(pool + 16384);
    ushort* As1 = (ushort*)(pool + 32768);
    ushort* Bs1 = (ushort*)(pool + 49152);
    float* rowD = (float*)pool;            // [128][32], aliases pool post-release
    float* colD = (float*)(pool + 16384);  // [128][8]

    const int tid = threadIdx.x;
    const int wave = tid >> 6, lane = tid & 63;
    const int bid = blockIdx.x, nb = gridDim.x;

    // ======== P0: build_perm (block 0 only) ========
    if (bid == 0) {
        int* lcnt = (int*)pool;            // [256][10]
        const int beg = tid * 32, end = beg + 32;
        int loc[10] = {0,0,0,0,0,0,0,0,0,0};
        for (int i = beg; i < end; ++i) {
            int c = label[i]; c = (c < 0) ? 0 : (c > 9 ? 9 : c);
            loc[c]++;
        }
        #pragma unroll
        for (int c = 0; c < 10; ++c) lcnt[tid * 10 + c] = loc[c];
        if (tid == 0) counter[0] = 0u;
        __syncthreads();

        for (int c = wave; c < 10; c += 4) {
            int s0 = lcnt[(lane*4+0)*10 + c], s1 = lcnt[(lane*4+1)*10 + c];
            int s2 = lcnt[(lane*4+2)*10 + c], s3 = lcnt[(lane*4+3)*10 + c];
            int tot = s0 + s1 + s2 + s3;
            int incl = tot;
            #pragma unroll
            for (int d = 1; d < 64; d <<= 1) {
                int up = __shfl_up(incl, d, 64);
                if (lane >= d) incl += up;
            }
            int excl = incl - tot;
            lcnt[(lane*4+0)*10 + c] = excl;
            lcnt[(lane*4+1)*10 + c] = excl + s0;
            lcnt[(lane*4+2)*10 + c] = excl + s0 + s1;
            lcnt[(lane*4+3)*10 + c] = excl + s0 + s1 + s2;
            if (lane == 63) ccount[c] = incl;
        }
        __syncthreads();

        if (tid == 0) {
            int run = 0, runT = 0;
            for (int c = 0; c < 10; ++c) {
                cstart[c] = run; classStartG[c] = run;
                int tpc = (ccount[c] + 127) >> 7;
                cumTilesG[c] = runT;
                run  += ccount[c];
                runT += tpc * tpc;
            }
            classStartG[10] = run; cumTilesG[10] = runT;
        }
        __syncthreads();

        int ofs[10];
        #pragma unroll
        for (int c = 0; c < 10; ++c) ofs[c] = lcnt[tid * 10 + c];
        for (int i = beg; i < end; ++i) {
            int c = label[i]; c = (c < 0) ? 0 : (c > 9 ? 9 : c);
            int pos = cstart[c] + ofs[c]++;
            perm[pos] = i;
            labelPerm[pos] = c;
        }
    }
    grid.sync();

    // ======== P1: normalize + permute + bf16 cast ========
    for (int g = bid; g < N_ROWS / 4; g += nb) {
        const int pos = g * 4 + wave;
        const int old = perm[pos];
        float4 v = reinterpret_cast<const float4*>(logits + (size_t)old * KDIM)[lane];
        float ss = v.x*v.x + v.y*v.y + v.z*v.z + v.w*v.w;
        #pragma unroll
        for (int off = 32; off >= 1; off >>= 1) ss += __shfl_xor(ss, off, 64);
        float inv = 1.0f / fmaxf(sqrtf(ss), 1e-8f);
        ushort4 o;
        o.x = f2bf(v.x * inv); o.y = f2bf(v.y * inv);
        o.z = f2bf(v.z * inv); o.w = f2bf(v.w * inv);
        reinterpret_cast<ushort4*>(xn + (size_t)pos * KDIM)[lane] = o;
    }
    grid.sync();

    // ======== P2: upper-tri 128-tiles -> pD partials (diff-label e sums) ====
    for (int t = bid; t < 2080; t += nb) {
        int tt = t, bi = 0;
        while (tt >= 64 - bi) { tt -= 64 - bi; ++bi; }
        const int bj = bi + tt;
        const bool isDiag = (bi == bj);
        const int rowBase = bi * 128, colBase = bj * 128;

        labLDS[tid] = labelPerm[(tid < 128) ? (rowBase + tid) : (colBase + tid - 128)];
        __builtin_amdgcn_sched_barrier(0);

        f32x4 acc[4][4] = {};
        kloop_pipe(xn, rowBase, colBase, acc, As0, Bs0, As1, Bs1, wave, lane);

        const int wr = wave >> 1, wc = wave & 1;
        const int lrow = lane & 15, lgrp = lane >> 4;
        float colAcc[4] = {0.f, 0.f, 0.f, 0.f};
        #pragma unroll
        for (int mi = 0; mi < 4; ++mi) {
            #pragma unroll
            for (int reg = 0; reg < 4; ++reg) {
                const int tr = wr * 64 + mi * 16 + lgrp * 4 + reg;
                const int rl = labLDS[tr];
                float rowAcc = 0.f;
                #pragma unroll
                for (int ni = 0; ni < 4; ++ni) {
                    const int tc = wc * 64 + ni * 16 + lrow;
                    float e = __builtin_amdgcn_exp2f(acc[mi][ni][reg] * EXPC);
                    float ed = (rl != labLDS[128 + tc]) ? e : 0.f;
                    rowAcc += ed;
                    colAcc[ni] += ed;
                }
                rowD[tr * 32 + wc * 16 + lrow] = rowAcc;
            }
        }
        if (!isDiag) {
            #pragma unroll
            for (int ni = 0; ni < 4; ++ni) {
                const int tc = wc * 64 + ni * 16 + lrow;
                colD[tc * 8 + wr * 4 + lgrp] = colAcc[ni];
            }
        }
        __syncthreads();

        if (tid < 128) {
            const float* p = rowD + tid * 32;
            float s = 0.f;
            #pragma unroll
            for (int k = 0; k < 8; ++k) {
                f32x4 v = *reinterpret_cast<const f32x4*>(p + k * 4);
                s += v[0] + v[1] + v[2] + v[3];
            }
            pD[(size_t)bj * N_ROWS + rowBase + tid] = s;
        } else if (!isDiag) {
            const int c2 = tid - 128;
            const float* p = colD + c2 * 8;
            f32x4 v0 = *reinterpret_cast<const f32x4*>(p);
            f32x4 v1 = *reinterpret_cast<const f32x4*>(p + 4);
            pD[(size_t)bi * N_ROWS + colBase + c2] =
                v0[0] + v0[1] + v0[2] + v0[3] + v1[0] + v1[1] + v1[2] + v1[3];
        }
        __syncthreads();   // release LDS (rowD/colD/labLDS) before next iteration
    }
    grid.sync();

    // ======== P4: same-class tiles -> log terms (Darr built per block) ======
    if (tid < 11) { labLDS[tid] = classStartG[tid]; labLDS[32 + tid] = cumTilesG[tid]; }
    __syncthreads();
    const int nTiles = labLDS[32 + 10];

    for (int t = bid; t < nTiles; t += nb) {
        int c = 0;
        while (c < 9 && t >= labLDS[32 + c + 1]) ++c;
        const int s = labLDS[c], e = labLDS[c + 1];
        const int nc = e - s;
        const int tps = (nc + 127) >> 7;
        const int lt = t - labLDS[32 + c];
        const int ti = lt / tps, tj = lt - ti * tps;
        const int rowBase = s + ti * 128, colBase = s + tj * 128;

        if (tid < 128) {   // per-block Darr for this tile's 128 rows (fixed order)
            float d = 0.f;
            for (int sl = 0; sl < 64; ++sl) d += pD[(size_t)sl * N_ROWS + rowBase + tid];
            DarrL[tid] = d;
        }
        __syncthreads();

        f32x4 acc[4][4] = {};
        kloop_pipe(xn, rowBase, colBase, acc, As0, Bs0, As1, Bs1, wave, lane);

        const int wr = wave >> 1, wc = wave & 1;
        const int lrow = lane & 15, lgrp = lane >> 4;
        float lsum = 0.f;
        #pragma unroll
        for (int mi = 0; mi < 4; ++mi) {
            #pragma unroll
            for (int reg = 0; reg < 4; ++reg) {
                const int tr = wr * 64 + mi * 16 + lgrp * 4 + reg;
                const int r = rowBase + tr;
                if (r < e) {
                    const float Dr = DarrL[tr];
                    #pragma unroll
                    for (int ni = 0; ni < 4; ++ni) {
                        const int cg2 = colBase + wc * 64 + ni * 16 + lrow;
                        if (cg2 < e && cg2 != r) {
                            float sim = acc[mi][ni][reg];
                            float ev = __builtin_amdgcn_exp2f(sim * EXPC);
                            lsum += __logf(ev + Dr) - TEMP_INV * sim;
                        }
                    }
                }
            }
        }
        redF[tid] = lsum;
        __syncthreads();
        for (int st = 128; st > 0; st >>= 1) {
            if (tid < st) redF[tid] += redF[tid + st];
            __syncthreads();
        }
        if (tid == 0) partial[t] = redF[0];
        __syncthreads();   // release redF/DarrL/pool before next iteration
    }

    // ======== tail: last-block-done deterministic reduction ========
    __threadfence();
    if (tid == 0) {
        unsigned int old = atomicAdd(counter, 1u);
        lastFlag = (old == (unsigned int)(nb - 1)) ? 1 : 0;
    }
    __syncthreads();
    if (lastFlag) {
        __threadfence();
        float s = 0.f;
        for (int i = tid; i < nTiles; i += 256) s += partial[i];
        redF[tid] = s;
        __syncthreads();
        for (int st = 128; st > 0; st >>= 1) {
            if (tid < st) redF[tid] += redF[tid + st];
            __syncthreads();
        }
        if (tid == 0) out[0] = redF[0] * (1.0f / 16384.0f);
    }
}

extern "C" void kernel_launch(void* const* d_in, const int* in_sizes, int n_in,
                              void* d_out, int out_size, void* d_ws, size_t ws_size,
                              hipStream_t stream)
{
    const float* logits = (const float*)d_in[0];
    const int*   label  = (const int*)d_in[1];
    float* out = (float*)d_out;

    char* ws = (char*)d_ws;
    ushort*       xn         = (ushort*)(ws);                              // 4 MB
    float*        pD         = (float*)(ws + (4u << 20));                  // 2 MB
    int*          perm       = (int*)(ws + (6u << 20));                    // 32 KB
    int*          labelPerm  = (int*)(ws + (6u << 20) + (32u << 10));      // 32 KB
    int*          classStartG= (int*)(ws + (6u << 20) + (64u << 10));      // 64 B
    int*          cumTilesG  = (int*)(ws + (6u << 20) + (64u << 10) + 256);// 64 B
    float*        partial    = (float*)(ws + (6u << 20) + (128u << 10));   // 16 KB
    unsigned int* counter    = (unsigned int*)(ws + (6u << 20) + (192u << 10)); // 4 B

    int occ = 0;
    hipOccupancyMaxActiveBlocksPerMultiprocessor(&occ, fused_all, 256, 0);
    if (occ < 1) occ = 1;
    int ncu = 0;
    hipDeviceGetAttribute(&ncu, hipDeviceAttributeMultiprocessorCount, 0);
    if (ncu < 1) ncu = 256;
    int nb = occ * ncu;
    if (nb > 512) nb = 512;

    void* kargs[] = {
        (void*)&logits, (void*)&label, (void*)&out,
        (void*)&xn, (void*)&pD, (void*)&perm, (void*)&labelPerm,
        (void*)&classStartG, (void*)&cumTilesG, (void*)&partial, (void*)&counter
    };
    hipLaunchCooperativeKernel(fused_all, dim3(nb), dim3(256), kargs, 0, stream);
}